// Round 4
// baseline (466.679 us; speedup 1.0000x reference)
//
#include <hip/hip_runtime.h>
#include <math.h>

#define B 2
#define S 256
#define H 768
#define L 50
#define E 512
#define W 10
#define NSPAN 2515
#define KTOP 102
#define D3 2304
#define N6 6912

// workspace float offsets
#define OFF_GOUT ((size_t)0)         // 512*768
#define OFF_EMB  ((size_t)393216)    // 512*768
#define OFF_G    ((size_t)786432)    // 512*6912
#define OFF_TOKD ((size_t)4325376)   // 512*8
#define OFF_MENT ((size_t)4329472)   // 5120
#define OFF_SJ   ((size_t)4334592)   // 5120
#define OFF_SI   ((size_t)4339712)   // 5120
#define OFF_INT  ((size_t)4345344)   // int region (2048 floats reserved)
#define OFF_EMBT ((size_t)4347392)   // 768*512
#define OFF_W1T  ((size_t)4740608)   // 2304*2304  (ends 10049024 floats = 40.2 MB)

// ---------------------------------------------------------------- edge grouping
__global__ __launch_bounds__(1024) void k_group(
    const int* __restrict__ esrc, const int* __restrict__ etgt,
    const int* __restrict__ elab, int* __restrict__ cnt,
    int* __restrict__ off, int* __restrict__ edges) {
    __shared__ int lcnt[L];
    __shared__ int loff[L];
    int t = threadIdx.x;  // t == global edge id, blockDim == B*E == 1024
    if (t < L) lcnt[t] = 0;
    __syncthreads();
    int lab = elab[t], src = esrc[t], tgt = etgt[t];
    bool valid = (lab >= 0) && (lab < L) && (src >= 0) && (src < S) && (tgt >= 0) && (tgt < S);
    int mypos = -1;
    if (valid) mypos = atomicAdd(&lcnt[lab], 1);
    __syncthreads();
    if (t == 0) {
        int acc = 0;
        for (int l = 0; l < L; l++) { loff[l] = acc; acc += lcnt[l]; }
    }
    __syncthreads();
    if (valid) edges[loff[lab] + mypos] = t;
    if (t < L) { cnt[t] = lcnt[t]; off[t] = loff[t]; }
}

// ---------------------------------------------------------------- generic 32x32 tiled transpose: out[C][R] = in[R][C]^T
__global__ __launch_bounds__(256) void k_trans(
    const float* __restrict__ in, float* __restrict__ out, int R, int C) {
    __shared__ float T[32][33];
    int c0 = blockIdx.x * 32, r0 = blockIdx.y * 32;
    int tid = threadIdx.x;
    int cc = tid & 31, r8 = tid >> 5;
#pragma unroll
    for (int i = 0; i < 4; i++) {
        int rr = r8 + 8 * i;
        T[rr][cc] = in[(size_t)(r0 + rr) * C + c0 + cc];
    }
    __syncthreads();
    int rr2 = tid & 31, c8 = tid >> 5;
#pragma unroll
    for (int i = 0; i < 4; i++) {
        int cc2 = c8 + 8 * i;
        out[(size_t)(c0 + cc2) * R + r0 + rr2] = T[rr2][cc2];
    }
}

// ---------------------------------------------------------------- GCN as per-label GEMM tiles
#define GK 384
__global__ __launch_bounds__(256) void k_gcn(
    const float* __restrict__ hidden, const float* __restrict__ gcnW,
    const float* __restrict__ gcnb, const int* __restrict__ cnt,
    const int* __restrict__ off, const int* __restrict__ edges,
    const int* __restrict__ esrc, const int* __restrict__ etgt,
    float* __restrict__ gout) {
    int l = blockIdx.y;
    int n = cnt[l];
    if (n == 0) return;
    int row0 = blockIdx.x * 64;
    int kbase = blockIdx.z * GK;
    __shared__ float Ws[32][68];   // [k][row], padded
    __shared__ float Xs[32][34];   // [k][edge]
    __shared__ int srow[32];
    __shared__ int trow[32];
    int tid = threadIdx.x;
    int tx = tid & 15, ty = tid >> 4;
    int o = off[l];
    for (int e0 = 0; e0 < n; e0 += 32) {
        int nv = min(32, n - e0);
        if (tid < 32) {
            int sr = 0, tr = 0;
            if (tid < nv) {
                int g = edges[o + e0 + tid];
                int bb = g / E;
                sr = (bb * S + esrc[g]) * H;
                tr = (bb * S + etgt[g]) * H;
            }
            srow[tid] = sr;
            trow[tid] = tr;
        }
        __syncthreads();
        float acc[4][2];
#pragma unroll
        for (int r = 0; r < 4; r++) { acc[r][0] = 0.f; acc[r][1] = 0.f; }
        for (int kc = 0; kc < GK; kc += 32) {
            int k0 = kbase + kc;
#pragma unroll
            for (int j = 0; j < 2; j++) {
                int f = tid + 256 * j;
                int r = f >> 3, kq = (f & 7) * 4;
                float4 v = *(const float4*)(gcnW + ((size_t)l * H + row0 + r) * H + k0 + kq);
                Ws[kq + 0][r] = v.x; Ws[kq + 1][r] = v.y;
                Ws[kq + 2][r] = v.z; Ws[kq + 3][r] = v.w;
            }
#pragma unroll
            for (int j = 0; j < 4; j++) {
                int f = tid + 256 * j;
                int e = f >> 5, kk = f & 31;
                Xs[kk][e] = hidden[srow[e] + k0 + kk];
            }
            __syncthreads();
#pragma unroll
            for (int k = 0; k < 32; k++) {
                float4 a = *(const float4*)&Ws[k][ty * 4];
                float2 x2 = *(const float2*)&Xs[k][tx * 2];
                acc[0][0] = fmaf(a.x, x2.x, acc[0][0]);
                acc[1][0] = fmaf(a.y, x2.x, acc[1][0]);
                acc[2][0] = fmaf(a.z, x2.x, acc[2][0]);
                acc[3][0] = fmaf(a.w, x2.x, acc[3][0]);
                acc[0][1] = fmaf(a.x, x2.y, acc[0][1]);
                acc[1][1] = fmaf(a.y, x2.y, acc[1][1]);
                acc[2][1] = fmaf(a.z, x2.y, acc[2][1]);
                acc[3][1] = fmaf(a.w, x2.y, acc[3][1]);
            }
            __syncthreads();
        }
        const float* bp = gcnb + l * H + row0 + ty * 4;
        bool addb = (blockIdx.z == 0);
#pragma unroll
        for (int e = 0; e < 2; e++) {
            int ei = tx * 2 + e;
            if (ei < nv) {
                int base = trow[ei] + row0 + ty * 4;
#pragma unroll
                for (int r = 0; r < 4; r++) {
                    float v = acc[r][e];
                    if (addb) v += bp[r];
                    atomicAdd(&gout[base + r], v);
                }
            }
        }
        __syncthreads();
    }
}

// ---------------------------------------------------------------- emb = hidden + relu(gout), plus per-token dots
__global__ __launch_bounds__(256) void k_embdots(
    const float* __restrict__ hidden, const float* __restrict__ gout,
    const float* __restrict__ attnw, const float* __restrict__ antw,
    float* __restrict__ emb, float* __restrict__ tokd) {
    int wave = threadIdx.x >> 6, lane = threadIdx.x & 63;
    int tok = blockIdx.x * 4 + wave;
    const float* hp = hidden + (size_t)tok * H;
    const float* gp = gout + (size_t)tok * H;
    float* ep = emb + (size_t)tok * H;
    float p[7] = {0, 0, 0, 0, 0, 0, 0};
#pragma unroll
    for (int m = 0; m < 12; m++) {
        int k = lane + 64 * m;
        float e = hp[k] + fmaxf(gp[k], 0.f);
        ep[k] = e;
        p[0] = fmaf(attnw[k], e, p[0]);
#pragma unroll
        for (int q = 0; q < 6; q++) p[1 + q] = fmaf(antw[q * H + k], e, p[1 + q]);
    }
#pragma unroll
    for (int q = 0; q < 7; q++) {
        float v = p[q];
#pragma unroll
        for (int d = 32; d; d >>= 1) v += __shfl_down(v, d);
        p[q] = v;
    }
    if (lane == 0) {
        float* o = tokd + (size_t)tok * 8;
#pragma unroll
        for (int q = 0; q < 7; q++) o[q] = p[q];
    }
}

// ---------------------------------------------------------------- G = emb @ W1-blocks^T via pre-transposed inputs
// __launch_bounds__(256,3): min 3 waves/EU -> VGPR cap ~170; kernel needs ~90.
// R3 lesson: default bound let allocator pick 48 VGPRs -> 83 MB/dispatch scratch spill.
__global__ __launch_bounds__(256, 3) void k_gemm(
    const float* __restrict__ embT, const float* __restrict__ W1T, float* __restrict__ G) {
    __shared__ float As[32][68];
    __shared__ float Bs[32][132];
    int n0 = blockIdx.x * 128;
    int m0 = blockIdx.y * 64;
    int blk = n0 / D3;          // 2304 % 128 == 0 -> tiles never straddle blocks
    int e0 = n0 - blk * D3;
    int tid = threadIdx.x;
    int tx = tid & 15, ty = tid >> 4;
    const float* Ap = embT + m0;                          // embT[k][m0+..]
    const float* Bp = W1T + (size_t)(blk * H) * D3 + e0;  // W1T[blk*768+k][e0+..]
    float4 pa[2], pb[4];
#pragma unroll
    for (int j = 0; j < 2; j++) {
        int f = tid + 256 * j;
        pa[j] = *(const float4*)(Ap + (size_t)(f >> 4) * 512 + (f & 15) * 4);
    }
#pragma unroll
    for (int j = 0; j < 4; j++) {
        int f = tid + 256 * j;
        pb[j] = *(const float4*)(Bp + (size_t)(f >> 5) * D3 + (f & 31) * 4);
    }
    float acc[4][8];
#pragma unroll
    for (int r = 0; r < 4; r++)
#pragma unroll
        for (int c = 0; c < 8; c++) acc[r][c] = 0.f;
    for (int kt = 0; kt < H; kt += 32) {
#pragma unroll
        for (int j = 0; j < 2; j++) {
            int f = tid + 256 * j;
            *(float4*)&As[f >> 4][(f & 15) * 4] = pa[j];
        }
#pragma unroll
        for (int j = 0; j < 4; j++) {
            int f = tid + 256 * j;
            *(float4*)&Bs[f >> 5][(f & 31) * 4] = pb[j];
        }
        __syncthreads();
        if (kt + 32 < H) {
            int kn = kt + 32;
#pragma unroll
            for (int j = 0; j < 2; j++) {
                int f = tid + 256 * j;
                pa[j] = *(const float4*)(Ap + (size_t)(kn + (f >> 4)) * 512 + (f & 15) * 4);
            }
#pragma unroll
            for (int j = 0; j < 4; j++) {
                int f = tid + 256 * j;
                pb[j] = *(const float4*)(Bp + (size_t)(kn + (f >> 5)) * D3 + (f & 31) * 4);
            }
        }
#pragma unroll
        for (int k = 0; k < 32; k++) {
            float4 a  = *(const float4*)&As[k][ty * 4];
            float4 b0 = *(const float4*)&Bs[k][tx * 4];
            float4 b1 = *(const float4*)&Bs[k][tx * 4 + 64];
            float av[4] = {a.x, a.y, a.z, a.w};
            float bv[8] = {b0.x, b0.y, b0.z, b0.w, b1.x, b1.y, b1.z, b1.w};
#pragma unroll
            for (int r = 0; r < 4; r++)
#pragma unroll
                for (int c = 0; c < 8; c++) acc[r][c] = fmaf(av[r], bv[c], acc[r][c]);
        }
        __syncthreads();
    }
#pragma unroll
    for (int r = 0; r < 4; r++) {
        float* gp = G + (size_t)(m0 + ty * 4 + r) * N6 + n0;
        *(float4*)(gp + tx * 4)      = make_float4(acc[r][0], acc[r][1], acc[r][2], acc[r][3]);
        *(float4*)(gp + tx * 4 + 64) = make_float4(acc[r][4], acc[r][5], acc[r][6], acc[r][7]);
    }
}

// ---------------------------------------------------------------- span kernel, e-chunked for parallelism
// ms_b2 / attn_b dropped: constant shifts, invariant under top-k / softmax.
__global__ __launch_bounds__(256) void k_span(
    const float* __restrict__ G, const float* __restrict__ tokd,
    const float* __restrict__ b1, const float* __restrict__ w2,
    float* __restrict__ ment, float* __restrict__ sjA, float* __restrict__ siA) {
    int ec = blockIdx.x;
    int start = blockIdx.y;
    int b = blockIdx.z;
    int nw = min(W, S - start);
    int tail = S - start;
    int base = (start <= S - W) ? start * W
             : (S - W + 1) * W + ((W - 1) * W / 2 - tail * (tail + 1) / 2);
    __shared__ float aw[W][W + 1];
    int tid = threadIdx.x;
    const float* td = tokd + (size_t)(b * S) * 8;
    if (tid < nw) {
        int w = tid;  // span of width w+1
        float sc[W];
        float mx = -3.0e38f;
        for (int j = 0; j <= w; j++) { sc[j] = td[(start + j) * 8]; mx = fmaxf(mx, sc[j]); }
        float sum = 0.f;
        for (int j = 0; j <= w; j++) { float e = expf(sc[j] - mx); aw[w][j] = e; sum += e; }
        float inv = 1.f / sum;
        for (int j = 0; j <= w; j++) aw[w][j] *= inv;
        if (ec == 0) {
            float sj = td[start * 8 + 1] + td[(start + w) * 8 + 2];
            float si = td[start * 8 + 4] + td[(start + w) * 8 + 5];
            for (int j = 0; j <= w; j++) {
                sj = fmaf(aw[w][j], td[(start + j) * 8 + 3], sj);
                si = fmaf(aw[w][j], td[(start + j) * 8 + 6], si);
            }
            sjA[b * NSPAN + base + w] = sj;
            siA[b * NSPAN + base + w] = si;
        }
    }
    __syncthreads();
    int e = ec * 256 + tid;
    const float* Gb = G + (size_t)(b * S) * N6;
    float a = Gb[(size_t)start * N6 + e] + b1[e];
    float w2e = w2[e];
    float cj[W], bm[W];
#pragma unroll
    for (int j = 0; j < W; j++) {
        if (j < nw) {
            cj[j] = Gb[(size_t)(start + j) * N6 + 2 * D3 + e];
            bm[j] = Gb[(size_t)(start + j) * N6 + D3 + e];
        } else { cj[j] = 0.f; bm[j] = 0.f; }
    }
    int lane = tid & 63;
#pragma unroll
    for (int w = 0; w < W; w++) {
        float v = 0.f;
        if (w < nw) {
            float pre = a + bm[w];
#pragma unroll
            for (int j = 0; j <= w; j++) pre = fmaf(aw[w][j], cj[j], pre);
            v = fmaxf(pre, 0.f) * w2e;
        }
#pragma unroll
        for (int d = 32; d; d >>= 1) v += __shfl_down(v, d);
        if (lane == 0 && w < nw) atomicAdd(&ment[b * NSPAN + base + w], v);
    }
}

// ---------------------------------------------------------------- fused top-k (radix select) + antecedent log-softmax
__global__ __launch_bounds__(256) void k_topkant(
    const float* __restrict__ ment, const float* __restrict__ sjA,
    const float* __restrict__ siA, const float* __restrict__ antb,
    float* __restrict__ out) {
    __shared__ unsigned int uv[NSPAN];
    __shared__ int hist[256];
    __shared__ int suf[256];
    __shared__ int cand_i[160];
    __shared__ unsigned int cand_u[160];
    __shared__ int ncand;
    __shared__ unsigned int s_prefix;
    __shared__ int s_kk;
    __shared__ float selj[KTOP];
    __shared__ float seli[KTOP];
    int b = blockIdx.x, tid = threadIdx.x;
    for (int n = tid; n < NSPAN; n += 256) {
        unsigned int u = __float_as_uint(ment[b * NSPAN + n]);
        uv[n] = (u & 0x80000000u) ? ~u : (u | 0x80000000u);
    }
    if (tid == 0) { s_prefix = 0u; s_kk = KTOP; ncand = 0; }
    __syncthreads();
    for (int pass = 3; pass >= 0; pass--) {
        int shift = pass * 8;
        hist[tid] = 0;
        __syncthreads();
        unsigned int pref = s_prefix;
        unsigned int pmask = (pass == 3) ? 0u : (0xFFFFFFFFu << (shift + 8));
        for (int n = tid; n < NSPAN; n += 256) {
            unsigned int u = uv[n];
            if ((u & pmask) == pref) atomicAdd(&hist[(u >> shift) & 255], 1);
        }
        __syncthreads();
        suf[tid] = hist[tid];
        __syncthreads();
        for (int d2 = 1; d2 < 256; d2 <<= 1) {
            int y = suf[tid] + ((tid + d2 < 256) ? suf[tid + d2] : 0);
            __syncthreads();
            suf[tid] = y;
            __syncthreads();
        }
        int kk = s_kk;
        __syncthreads();
        if (suf[tid] >= kk && (tid == 255 || suf[tid + 1] < kk)) {
            s_prefix = pref | ((unsigned int)tid << shift);
            s_kk = kk - ((tid == 255) ? 0 : suf[tid + 1]);
        }
        __syncthreads();
    }
    unsigned int uk = s_prefix;   // exact k-th largest key
    for (int n = tid; n < NSPAN; n += 256) {
        if (uv[n] >= uk) {
            int p = atomicAdd(&ncand, 1);
            if (p < 160) { cand_i[p] = n; cand_u[p] = uv[n]; }
        }
    }
    __syncthreads();
    int nc = min(ncand, 160);
    for (int c = tid; c < nc; c += 256) {
        unsigned int u = cand_u[c];
        int idx = cand_i[c];
        int rank = 0;
        for (int d = 0; d < nc; d++) {
            unsigned int ud = cand_u[d];
            if (ud > u || (ud == u && cand_i[d] < idx)) rank++;
        }
        if (rank < KTOP) {
            selj[rank] = sjA[b * NSPAN + idx];
            seli[rank] = siA[b * NSPAN + idx];
        }
    }
    __syncthreads();
    // antecedent rows: wave per row, lanes cover cols {lane, lane+64} of 103
    float ab = antb[0];
    int wave = tid >> 6, lane = tid & 63;
    for (int i = wave; i < KTOP; i += 4) {
        float si = seli[i];
        float v0, v1;
        // col c0 = lane
        if (lane == 0) v0 = 0.f;
        else {
            int j = lane - 1;
            v0 = (j >= i) ? -1e10f : (selj[j] + si + ab);
        }
        // col c1 = lane + 64 (valid while <= KTOP i.e. lane <= 38)
        int c1 = lane + 64;
        bool v1ok = (c1 <= KTOP);
        if (v1ok) {
            int j = c1 - 1;
            v1 = (j >= i) ? -1e10f : (selj[j] + si + ab);
        } else v1 = -3.0e38f;
        float mx = fmaxf(v0, v1);
#pragma unroll
        for (int d = 32; d; d >>= 1) mx = fmaxf(mx, __shfl_down(mx, d));
        mx = __shfl(mx, 0);
        float e0 = expf(v0 - mx);
        float e1 = v1ok ? expf(v1 - mx) : 0.f;
        float sm = e0 + e1;
#pragma unroll
        for (int d = 32; d; d >>= 1) sm += __shfl_down(sm, d);
        sm = __shfl(sm, 0);
        float* op = out + (size_t)(b * KTOP + i) * (KTOP + 1);
        op[lane] = logf(e0 / sm + 1e-10f);
        if (v1ok) op[c1] = logf(e1 / sm + 1e-10f);
    }
}

extern "C" void kernel_launch(void* const* d_in, const int* in_sizes, int n_in,
                              void* d_out, int out_size, void* d_ws, size_t ws_size,
                              hipStream_t stream) {
    (void)in_sizes; (void)n_in; (void)out_size; (void)ws_size;
    const float* hidden = (const float*)d_in[0];
    const int*   esrc   = (const int*)d_in[2];
    const int*   etgt   = (const int*)d_in[3];
    const int*   elab   = (const int*)d_in[4];
    const float* gcnW   = (const float*)d_in[5];
    const float* gcnb   = (const float*)d_in[6];
    const float* attnw  = (const float*)d_in[7];
    const float* msW1   = (const float*)d_in[9];
    const float* msb1   = (const float*)d_in[10];
    const float* msw2   = (const float*)d_in[11];
    const float* antw   = (const float*)d_in[13];
    const float* antb   = (const float*)d_in[14];
    float* out = (float*)d_out;

    float* wsf  = (float*)d_ws;
    float* gout = wsf + OFF_GOUT;
    float* emb  = wsf + OFF_EMB;
    float* G    = wsf + OFF_G;
    float* tokd = wsf + OFF_TOKD;
    float* ment = wsf + OFF_MENT;
    float* sjA  = wsf + OFF_SJ;
    float* siA  = wsf + OFF_SI;
    float* embT = wsf + OFF_EMBT;
    float* W1T  = wsf + OFF_W1T;
    int* wsi   = (int*)(wsf + OFF_INT);
    int* cnt   = wsi;
    int* off   = wsi + 64;
    int* edges = wsi + 128;

    hipMemsetAsync(gout, 0, (size_t)B * S * H * sizeof(float), stream);
    hipMemsetAsync(ment, 0, (size_t)B * NSPAN * sizeof(float), stream);
    k_group<<<1, B * E, 0, stream>>>(esrc, etgt, elab, cnt, off, edges);
    k_trans<<<dim3(D3 / 32, D3 / 32), 256, 0, stream>>>(msW1, W1T, D3, D3);
    k_gcn<<<dim3(12, L, 2), 256, 0, stream>>>(hidden, gcnW, gcnb, cnt, off, edges, esrc, etgt, gout);
    k_embdots<<<B * S / 4, 256, 0, stream>>>(hidden, gout, attnw, antw, emb, tokd);
    k_trans<<<dim3(H / 32, (B * S) / 32), 256, 0, stream>>>(emb, embT, B * S, H);
    k_gemm<<<dim3(N6 / 128, B * S / 64), 256, 0, stream>>>(embT, W1T, G);
    k_span<<<dim3(D3 / 256, S, B), 256, 0, stream>>>(G, tokd, msb1, msw2, ment, sjA, siA);
    k_topkant<<<B, 256, 0, stream>>>(ment, sjA, siA, antb, out);
}

// Round 5
// 435.014 us; speedup vs baseline: 1.0728x; 1.0728x over previous
//
#include <hip/hip_runtime.h>
#include <math.h>

#define B 2
#define S 256
#define H 768
#define L 50
#define E 512
#define W 10
#define NSPAN 2515
#define KTOP 102
#define D3 2304
#define N6 6912

// workspace float offsets
#define OFF_GOUT ((size_t)0)         // 512*768
#define OFF_EMB  ((size_t)393216)    // 512*768
#define OFF_G    ((size_t)786432)    // 512*6912
#define OFF_TOKD ((size_t)4325376)   // 512*8
#define OFF_MENT ((size_t)4329472)   // 5120
#define OFF_SJ   ((size_t)4334592)   // 5120
#define OFF_SI   ((size_t)4339712)   // 5120
#define OFF_INT  ((size_t)4345344)   // int region (2048 floats reserved)
#define OFF_EMBT ((size_t)4347392)   // 768*512
#define OFF_W1T  ((size_t)4740608)   // 2304*2304  (ends 10049024 floats = 40.2 MB)

// ---------------------------------------------------------------- edge grouping
__global__ __launch_bounds__(1024) void k_group(
    const int* __restrict__ esrc, const int* __restrict__ etgt,
    const int* __restrict__ elab, int* __restrict__ cnt,
    int* __restrict__ off, int* __restrict__ edges) {
    __shared__ int lcnt[L];
    __shared__ int loff[L];
    int t = threadIdx.x;  // t == global edge id, blockDim == B*E == 1024
    if (t < L) lcnt[t] = 0;
    __syncthreads();
    int lab = elab[t], src = esrc[t], tgt = etgt[t];
    bool valid = (lab >= 0) && (lab < L) && (src >= 0) && (src < S) && (tgt >= 0) && (tgt < S);
    int mypos = -1;
    if (valid) mypos = atomicAdd(&lcnt[lab], 1);
    __syncthreads();
    if (t == 0) {
        int acc = 0;
        for (int l = 0; l < L; l++) { loff[l] = acc; acc += lcnt[l]; }
    }
    __syncthreads();
    if (valid) edges[loff[lab] + mypos] = t;
    if (t < L) { cnt[t] = lcnt[t]; off[t] = loff[t]; }
}

// ---------------------------------------------------------------- generic 32x32 tiled transpose: out[C][R] = in[R][C]^T
__global__ __launch_bounds__(256) void k_trans(
    const float* __restrict__ in, float* __restrict__ out, int R, int C) {
    __shared__ float T[32][33];
    int c0 = blockIdx.x * 32, r0 = blockIdx.y * 32;
    int tid = threadIdx.x;
    int cc = tid & 31, r8 = tid >> 5;
#pragma unroll
    for (int i = 0; i < 4; i++) {
        int rr = r8 + 8 * i;
        T[rr][cc] = in[(size_t)(r0 + rr) * C + c0 + cc];
    }
    __syncthreads();
    int rr2 = tid & 31, c8 = tid >> 5;
#pragma unroll
    for (int i = 0; i < 4; i++) {
        int cc2 = c8 + 8 * i;
        out[(size_t)(c0 + cc2) * R + r0 + rr2] = T[rr2][cc2];
    }
}

// ---------------------------------------------------------------- GCN as per-label GEMM tiles
#define GK 384
__global__ __launch_bounds__(256) void k_gcn(
    const float* __restrict__ hidden, const float* __restrict__ gcnW,
    const float* __restrict__ gcnb, const int* __restrict__ cnt,
    const int* __restrict__ off, const int* __restrict__ edges,
    const int* __restrict__ esrc, const int* __restrict__ etgt,
    float* __restrict__ gout) {
    int l = blockIdx.y;
    int n = cnt[l];
    if (n == 0) return;
    int row0 = blockIdx.x * 64;
    int kbase = blockIdx.z * GK;
    __shared__ float Ws[32][68];   // [k][row], padded
    __shared__ float Xs[32][34];   // [k][edge]
    __shared__ int srow[32];
    __shared__ int trow[32];
    int tid = threadIdx.x;
    int tx = tid & 15, ty = tid >> 4;
    int o = off[l];
    for (int e0 = 0; e0 < n; e0 += 32) {
        int nv = min(32, n - e0);
        if (tid < 32) {
            int sr = 0, tr = 0;
            if (tid < nv) {
                int g = edges[o + e0 + tid];
                int bb = g / E;
                sr = (bb * S + esrc[g]) * H;
                tr = (bb * S + etgt[g]) * H;
            }
            srow[tid] = sr;
            trow[tid] = tr;
        }
        __syncthreads();
        float acc[4][2];
#pragma unroll
        for (int r = 0; r < 4; r++) { acc[r][0] = 0.f; acc[r][1] = 0.f; }
        for (int kc = 0; kc < GK; kc += 32) {
            int k0 = kbase + kc;
#pragma unroll
            for (int j = 0; j < 2; j++) {
                int f = tid + 256 * j;
                int r = f >> 3, kq = (f & 7) * 4;
                float4 v = *(const float4*)(gcnW + ((size_t)l * H + row0 + r) * H + k0 + kq);
                Ws[kq + 0][r] = v.x; Ws[kq + 1][r] = v.y;
                Ws[kq + 2][r] = v.z; Ws[kq + 3][r] = v.w;
            }
#pragma unroll
            for (int j = 0; j < 4; j++) {
                int f = tid + 256 * j;
                int e = f >> 5, kk = f & 31;
                Xs[kk][e] = hidden[srow[e] + k0 + kk];
            }
            __syncthreads();
#pragma unroll
            for (int k = 0; k < 32; k++) {
                float4 a = *(const float4*)&Ws[k][ty * 4];
                float2 x2 = *(const float2*)&Xs[k][tx * 2];
                acc[0][0] = fmaf(a.x, x2.x, acc[0][0]);
                acc[1][0] = fmaf(a.y, x2.x, acc[1][0]);
                acc[2][0] = fmaf(a.z, x2.x, acc[2][0]);
                acc[3][0] = fmaf(a.w, x2.x, acc[3][0]);
                acc[0][1] = fmaf(a.x, x2.y, acc[0][1]);
                acc[1][1] = fmaf(a.y, x2.y, acc[1][1]);
                acc[2][1] = fmaf(a.z, x2.y, acc[2][1]);
                acc[3][1] = fmaf(a.w, x2.y, acc[3][1]);
            }
            __syncthreads();
        }
        const float* bp = gcnb + l * H + row0 + ty * 4;
        bool addb = (blockIdx.z == 0);
#pragma unroll
        for (int e = 0; e < 2; e++) {
            int ei = tx * 2 + e;
            if (ei < nv) {
                int base = trow[ei] + row0 + ty * 4;
#pragma unroll
                for (int r = 0; r < 4; r++) {
                    float v = acc[r][e];
                    if (addb) v += bp[r];
                    atomicAdd(&gout[base + r], v);
                }
            }
        }
        __syncthreads();
    }
}

// ---------------------------------------------------------------- emb = hidden + relu(gout), plus per-token dots
__global__ __launch_bounds__(256) void k_embdots(
    const float* __restrict__ hidden, const float* __restrict__ gout,
    const float* __restrict__ attnw, const float* __restrict__ antw,
    float* __restrict__ emb, float* __restrict__ tokd) {
    int wave = threadIdx.x >> 6, lane = threadIdx.x & 63;
    int tok = blockIdx.x * 4 + wave;
    const float* hp = hidden + (size_t)tok * H;
    const float* gp = gout + (size_t)tok * H;
    float* ep = emb + (size_t)tok * H;
    float p[7] = {0, 0, 0, 0, 0, 0, 0};
#pragma unroll
    for (int m = 0; m < 12; m++) {
        int k = lane + 64 * m;
        float e = hp[k] + fmaxf(gp[k], 0.f);
        ep[k] = e;
        p[0] = fmaf(attnw[k], e, p[0]);
#pragma unroll
        for (int q = 0; q < 6; q++) p[1 + q] = fmaf(antw[q * H + k], e, p[1 + q]);
    }
#pragma unroll
    for (int q = 0; q < 7; q++) {
        float v = p[q];
#pragma unroll
        for (int d = 32; d; d >>= 1) v += __shfl_down(v, d);
        p[q] = v;
    }
    if (lane == 0) {
        float* o = tokd + (size_t)tok * 8;
#pragma unroll
        for (int q = 0; q < 7; q++) o[q] = p[q];
    }
}

// ---------------------------------------------------------------- G = emb @ W1-blocks^T via pre-transposed inputs
// R3/R4 lesson: acc/prefetch ARRAYS were demoted to scratch (VGPR=48, 83 MB
// spill writes/dispatch). All accumulators and prefetch values are NAMED
// scalars here — cannot be demoted.
__global__ __launch_bounds__(256, 3) void k_gemm(
    const float* __restrict__ embT, const float* __restrict__ W1T, float* __restrict__ G) {
    __shared__ float As[32][68];
    __shared__ float Bs[32][132];
    int n0 = blockIdx.x * 128;
    int m0 = blockIdx.y * 64;
    int blk = n0 / D3;          // 2304 % 128 == 0 -> tiles never straddle blocks
    int e0 = n0 - blk * D3;
    int tid = threadIdx.x;
    int tx = tid & 15, ty = tid >> 4;
    const float* Ap = embT + m0;                          // embT[k][m0+..]
    const float* Bp = W1T + (size_t)(blk * H) * D3 + e0;  // W1T[blk*768+k][e0+..]
    // per-thread staging coords (A: 512 threads-worth over 2 chunks; B: 4 chunks)
    int ar0 = tid >> 4, ac0 = (tid & 15) * 4;             // chunk j: row ar0+16j? no: f=tid+256j -> row f>>4
    int ar1 = (tid + 256) >> 4, ac1 = ((tid + 256) & 15) * 4;
    int br0 = tid >> 5, bc0 = (tid & 31) * 4;
    int br1 = (tid + 256) >> 5, bc1 = ((tid + 256) & 31) * 4;
    int br2 = (tid + 512) >> 5, bc2 = ((tid + 512) & 31) * 4;
    int br3 = (tid + 768) >> 5, bc3 = ((tid + 768) & 31) * 4;
    float4 pa0 = *(const float4*)(Ap + (size_t)ar0 * 512 + ac0);
    float4 pa1 = *(const float4*)(Ap + (size_t)ar1 * 512 + ac1);
    float4 pb0 = *(const float4*)(Bp + (size_t)br0 * D3 + bc0);
    float4 pb1 = *(const float4*)(Bp + (size_t)br1 * D3 + bc1);
    float4 pb2 = *(const float4*)(Bp + (size_t)br2 * D3 + bc2);
    float4 pb3 = *(const float4*)(Bp + (size_t)br3 * D3 + bc3);
    float c00 = 0.f, c01 = 0.f, c02 = 0.f, c03 = 0.f, c04 = 0.f, c05 = 0.f, c06 = 0.f, c07 = 0.f;
    float c10 = 0.f, c11 = 0.f, c12 = 0.f, c13 = 0.f, c14 = 0.f, c15 = 0.f, c16 = 0.f, c17 = 0.f;
    float c20 = 0.f, c21 = 0.f, c22 = 0.f, c23 = 0.f, c24 = 0.f, c25 = 0.f, c26 = 0.f, c27 = 0.f;
    float c30 = 0.f, c31 = 0.f, c32 = 0.f, c33 = 0.f, c34 = 0.f, c35 = 0.f, c36 = 0.f, c37 = 0.f;
    for (int kt = 0; kt < H; kt += 32) {
        *(float4*)&As[ar0][ac0] = pa0;
        *(float4*)&As[ar1][ac1] = pa1;
        *(float4*)&Bs[br0][bc0] = pb0;
        *(float4*)&Bs[br1][bc1] = pb1;
        *(float4*)&Bs[br2][bc2] = pb2;
        *(float4*)&Bs[br3][bc3] = pb3;
        __syncthreads();
        if (kt + 32 < H) {
            const float* Apn = Ap + (size_t)(kt + 32) * 512;
            const float* Bpn = Bp + (size_t)(kt + 32) * D3;
            pa0 = *(const float4*)(Apn + (size_t)ar0 * 512 + ac0);
            pa1 = *(const float4*)(Apn + (size_t)ar1 * 512 + ac1);
            pb0 = *(const float4*)(Bpn + (size_t)br0 * D3 + bc0);
            pb1 = *(const float4*)(Bpn + (size_t)br1 * D3 + bc1);
            pb2 = *(const float4*)(Bpn + (size_t)br2 * D3 + bc2);
            pb3 = *(const float4*)(Bpn + (size_t)br3 * D3 + bc3);
        }
#pragma unroll
        for (int k = 0; k < 32; k++) {
            float4 av = *(const float4*)&As[k][ty * 4];
            float4 b0 = *(const float4*)&Bs[k][tx * 4];
            float4 b1 = *(const float4*)&Bs[k][tx * 4 + 64];
            c00 = fmaf(av.x, b0.x, c00); c01 = fmaf(av.x, b0.y, c01);
            c02 = fmaf(av.x, b0.z, c02); c03 = fmaf(av.x, b0.w, c03);
            c04 = fmaf(av.x, b1.x, c04); c05 = fmaf(av.x, b1.y, c05);
            c06 = fmaf(av.x, b1.z, c06); c07 = fmaf(av.x, b1.w, c07);
            c10 = fmaf(av.y, b0.x, c10); c11 = fmaf(av.y, b0.y, c11);
            c12 = fmaf(av.y, b0.z, c12); c13 = fmaf(av.y, b0.w, c13);
            c14 = fmaf(av.y, b1.x, c14); c15 = fmaf(av.y, b1.y, c15);
            c16 = fmaf(av.y, b1.z, c16); c17 = fmaf(av.y, b1.w, c17);
            c20 = fmaf(av.z, b0.x, c20); c21 = fmaf(av.z, b0.y, c21);
            c22 = fmaf(av.z, b0.z, c22); c23 = fmaf(av.z, b0.w, c23);
            c24 = fmaf(av.z, b1.x, c24); c25 = fmaf(av.z, b1.y, c25);
            c26 = fmaf(av.z, b1.z, c26); c27 = fmaf(av.z, b1.w, c27);
            c30 = fmaf(av.w, b0.x, c30); c31 = fmaf(av.w, b0.y, c31);
            c32 = fmaf(av.w, b0.z, c32); c33 = fmaf(av.w, b0.w, c33);
            c34 = fmaf(av.w, b1.x, c34); c35 = fmaf(av.w, b1.y, c35);
            c36 = fmaf(av.w, b1.z, c36); c37 = fmaf(av.w, b1.w, c37);
        }
        __syncthreads();
    }
    float* g0 = G + (size_t)(m0 + ty * 4 + 0) * N6 + n0;
    float* g1 = G + (size_t)(m0 + ty * 4 + 1) * N6 + n0;
    float* g2 = G + (size_t)(m0 + ty * 4 + 2) * N6 + n0;
    float* g3 = G + (size_t)(m0 + ty * 4 + 3) * N6 + n0;
    *(float4*)(g0 + tx * 4)      = make_float4(c00, c01, c02, c03);
    *(float4*)(g0 + tx * 4 + 64) = make_float4(c04, c05, c06, c07);
    *(float4*)(g1 + tx * 4)      = make_float4(c10, c11, c12, c13);
    *(float4*)(g1 + tx * 4 + 64) = make_float4(c14, c15, c16, c17);
    *(float4*)(g2 + tx * 4)      = make_float4(c20, c21, c22, c23);
    *(float4*)(g2 + tx * 4 + 64) = make_float4(c24, c25, c26, c27);
    *(float4*)(g3 + tx * 4)      = make_float4(c30, c31, c32, c33);
    *(float4*)(g3 + tx * 4 + 64) = make_float4(c34, c35, c36, c37);
}

// ---------------------------------------------------------------- span kernel, e-chunked for parallelism
// ms_b2 / attn_b dropped: constant shifts, invariant under top-k / softmax.
__global__ __launch_bounds__(256) void k_span(
    const float* __restrict__ G, const float* __restrict__ tokd,
    const float* __restrict__ b1, const float* __restrict__ w2,
    float* __restrict__ ment, float* __restrict__ sjA, float* __restrict__ siA) {
    int ec = blockIdx.x;
    int start = blockIdx.y;
    int b = blockIdx.z;
    int nw = min(W, S - start);
    int tail = S - start;
    int base = (start <= S - W) ? start * W
             : (S - W + 1) * W + ((W - 1) * W / 2 - tail * (tail + 1) / 2);
    __shared__ float aw[W][W + 1];
    int tid = threadIdx.x;
    const float* td = tokd + (size_t)(b * S) * 8;
    if (tid < nw) {
        int w = tid;  // span of width w+1
        float sc[W];
        float mx = -3.0e38f;
        for (int j = 0; j <= w; j++) { sc[j] = td[(start + j) * 8]; mx = fmaxf(mx, sc[j]); }
        float sum = 0.f;
        for (int j = 0; j <= w; j++) { float e = expf(sc[j] - mx); aw[w][j] = e; sum += e; }
        float inv = 1.f / sum;
        for (int j = 0; j <= w; j++) aw[w][j] *= inv;
        if (ec == 0) {
            float sj = td[start * 8 + 1] + td[(start + w) * 8 + 2];
            float si = td[start * 8 + 4] + td[(start + w) * 8 + 5];
            for (int j = 0; j <= w; j++) {
                sj = fmaf(aw[w][j], td[(start + j) * 8 + 3], sj);
                si = fmaf(aw[w][j], td[(start + j) * 8 + 6], si);
            }
            sjA[b * NSPAN + base + w] = sj;
            siA[b * NSPAN + base + w] = si;
        }
    }
    __syncthreads();
    int e = ec * 256 + tid;
    const float* Gb = G + (size_t)(b * S) * N6;
    float a = Gb[(size_t)start * N6 + e] + b1[e];
    float w2e = w2[e];
    float cj[W], bm[W];
#pragma unroll
    for (int j = 0; j < W; j++) {
        if (j < nw) {
            cj[j] = Gb[(size_t)(start + j) * N6 + 2 * D3 + e];
            bm[j] = Gb[(size_t)(start + j) * N6 + D3 + e];
        } else { cj[j] = 0.f; bm[j] = 0.f; }
    }
    int lane = tid & 63;
#pragma unroll
    for (int w = 0; w < W; w++) {
        float v = 0.f;
        if (w < nw) {
            float pre = a + bm[w];
#pragma unroll
            for (int j = 0; j <= w; j++) pre = fmaf(aw[w][j], cj[j], pre);
            v = fmaxf(pre, 0.f) * w2e;
        }
#pragma unroll
        for (int d = 32; d; d >>= 1) v += __shfl_down(v, d);
        if (lane == 0 && w < nw) atomicAdd(&ment[b * NSPAN + base + w], v);
    }
}

// ---------------------------------------------------------------- fused top-k (radix select) + antecedent log-softmax
// hist is wave-replicated: float-bit top bytes cluster heavily, and same-address
// LDS atomics serialize; 4 replicas cut the contention 4x.
__global__ __launch_bounds__(256) void k_topkant(
    const float* __restrict__ ment, const float* __restrict__ sjA,
    const float* __restrict__ siA, const float* __restrict__ antb,
    float* __restrict__ out) {
    __shared__ unsigned int uv[NSPAN];
    __shared__ int hist[4][256];
    __shared__ int suf[256];
    __shared__ int cand_i[160];
    __shared__ unsigned int cand_u[160];
    __shared__ int ncand;
    __shared__ unsigned int s_prefix;
    __shared__ int s_kk;
    __shared__ float selj[KTOP];
    __shared__ float seli[KTOP];
    int b = blockIdx.x, tid = threadIdx.x;
    int wave = tid >> 6, lane = tid & 63;
    for (int n = tid; n < NSPAN; n += 256) {
        unsigned int u = __float_as_uint(ment[b * NSPAN + n]);
        uv[n] = (u & 0x80000000u) ? ~u : (u | 0x80000000u);
    }
    if (tid == 0) { s_prefix = 0u; s_kk = KTOP; ncand = 0; }
    __syncthreads();
    for (int pass = 3; pass >= 0; pass--) {
        int shift = pass * 8;
#pragma unroll
        for (int q = 0; q < 4; q++) hist[q][tid] = 0;
        __syncthreads();
        unsigned int pref = s_prefix;
        unsigned int pmask = (pass == 3) ? 0u : (0xFFFFFFFFu << (shift + 8));
        for (int n = tid; n < NSPAN; n += 256) {
            unsigned int u = uv[n];
            if ((u & pmask) == pref) atomicAdd(&hist[wave][(u >> shift) & 255], 1);
        }
        __syncthreads();
        suf[tid] = hist[0][tid] + hist[1][tid] + hist[2][tid] + hist[3][tid];
        __syncthreads();
        for (int d2 = 1; d2 < 256; d2 <<= 1) {
            int y = suf[tid] + ((tid + d2 < 256) ? suf[tid + d2] : 0);
            __syncthreads();
            suf[tid] = y;
            __syncthreads();
        }
        int kk = s_kk;
        __syncthreads();
        if (suf[tid] >= kk && (tid == 255 || suf[tid + 1] < kk)) {
            s_prefix = pref | ((unsigned int)tid << shift);
            s_kk = kk - ((tid == 255) ? 0 : suf[tid + 1]);
        }
        __syncthreads();
    }
    unsigned int uk = s_prefix;   // exact k-th largest key
    for (int n = tid; n < NSPAN; n += 256) {
        if (uv[n] >= uk) {
            int p = atomicAdd(&ncand, 1);
            if (p < 160) { cand_i[p] = n; cand_u[p] = uv[n]; }
        }
    }
    __syncthreads();
    int nc = min(ncand, 160);
    for (int c = tid; c < nc; c += 256) {
        unsigned int u = cand_u[c];
        int idx = cand_i[c];
        int rank = 0;
        for (int d = 0; d < nc; d++) {
            unsigned int ud = cand_u[d];
            if (ud > u || (ud == u && cand_i[d] < idx)) rank++;
        }
        if (rank < KTOP) {
            selj[rank] = sjA[b * NSPAN + idx];
            seli[rank] = siA[b * NSPAN + idx];
        }
    }
    __syncthreads();
    // antecedent rows: wave per row, lanes cover cols {lane, lane+64} of 103
    float ab = antb[0];
    for (int i = wave; i < KTOP; i += 4) {
        float si = seli[i];
        float v0, v1;
        if (lane == 0) v0 = 0.f;
        else {
            int j = lane - 1;
            v0 = (j >= i) ? -1e10f : (selj[j] + si + ab);
        }
        int c1 = lane + 64;
        bool v1ok = (c1 <= KTOP);
        if (v1ok) {
            int j = c1 - 1;
            v1 = (j >= i) ? -1e10f : (selj[j] + si + ab);
        } else v1 = -3.0e38f;
        float mx = fmaxf(v0, v1);
#pragma unroll
        for (int d = 32; d; d >>= 1) mx = fmaxf(mx, __shfl_down(mx, d));
        mx = __shfl(mx, 0);
        float e0 = expf(v0 - mx);
        float e1 = v1ok ? expf(v1 - mx) : 0.f;
        float sm = e0 + e1;
#pragma unroll
        for (int d = 32; d; d >>= 1) sm += __shfl_down(sm, d);
        sm = __shfl(sm, 0);
        float* op = out + (size_t)(b * KTOP + i) * (KTOP + 1);
        op[lane] = logf(e0 / sm + 1e-10f);
        if (v1ok) op[c1] = logf(e1 / sm + 1e-10f);
    }
}

extern "C" void kernel_launch(void* const* d_in, const int* in_sizes, int n_in,
                              void* d_out, int out_size, void* d_ws, size_t ws_size,
                              hipStream_t stream) {
    (void)in_sizes; (void)n_in; (void)out_size; (void)ws_size;
    const float* hidden = (const float*)d_in[0];
    const int*   esrc   = (const int*)d_in[2];
    const int*   etgt   = (const int*)d_in[3];
    const int*   elab   = (const int*)d_in[4];
    const float* gcnW   = (const float*)d_in[5];
    const float* gcnb   = (const float*)d_in[6];
    const float* attnw  = (const float*)d_in[7];
    const float* msW1   = (const float*)d_in[9];
    const float* msb1   = (const float*)d_in[10];
    const float* msw2   = (const float*)d_in[11];
    const float* antw   = (const float*)d_in[13];
    const float* antb   = (const float*)d_in[14];
    float* out = (float*)d_out;

    float* wsf  = (float*)d_ws;
    float* gout = wsf + OFF_GOUT;
    float* emb  = wsf + OFF_EMB;
    float* G    = wsf + OFF_G;
    float* tokd = wsf + OFF_TOKD;
    float* ment = wsf + OFF_MENT;
    float* sjA  = wsf + OFF_SJ;
    float* siA  = wsf + OFF_SI;
    float* embT = wsf + OFF_EMBT;
    float* W1T  = wsf + OFF_W1T;
    int* wsi   = (int*)(wsf + OFF_INT);
    int* cnt   = wsi;
    int* off   = wsi + 64;
    int* edges = wsi + 128;

    hipMemsetAsync(gout, 0, (size_t)B * S * H * sizeof(float), stream);
    hipMemsetAsync(ment, 0, (size_t)B * NSPAN * sizeof(float), stream);
    k_group<<<1, B * E, 0, stream>>>(esrc, etgt, elab, cnt, off, edges);
    k_trans<<<dim3(D3 / 32, D3 / 32), 256, 0, stream>>>(msW1, W1T, D3, D3);
    k_gcn<<<dim3(12, L, 2), 256, 0, stream>>>(hidden, gcnW, gcnb, cnt, off, edges, esrc, etgt, gout);
    k_embdots<<<B * S / 4, 256, 0, stream>>>(hidden, gout, attnw, antw, emb, tokd);
    k_trans<<<dim3(H / 32, (B * S) / 32), 256, 0, stream>>>(emb, embT, B * S, H);
    k_gemm<<<dim3(N6 / 128, B * S / 64), 256, 0, stream>>>(embT, W1T, G);
    k_span<<<dim3(D3 / 256, S, B), 256, 0, stream>>>(G, tokd, msb1, msw2, ment, sjA, siA);
    k_topkant<<<B, 256, 0, stream>>>(ment, sjA, siA, antb, out);
}

// Round 6
// 432.899 us; speedup vs baseline: 1.0780x; 1.0049x over previous
//
#include <hip/hip_runtime.h>
#include <math.h>

#define B 2
#define S 256
#define H 768
#define L 50
#define E 512
#define W 10
#define NSPAN 2515
#define KTOP 102
#define D3 2304
#define N6 6912

// workspace float offsets
#define OFF_GOUT ((size_t)0)         // 512*768
#define OFF_EMB  ((size_t)393216)    // 512*768
#define OFF_G    ((size_t)786432)    // 512*6912
#define OFF_TOKD ((size_t)4325376)   // 512*8
#define OFF_MENT ((size_t)4329472)   // 5120
#define OFF_SJ   ((size_t)4334592)   // 5120
#define OFF_SI   ((size_t)4339712)   // 5120
#define OFF_INT  ((size_t)4345344)   // int region (2048 floats reserved)
#define OFF_EMBT ((size_t)4347392)   // 768*512
#define OFF_W1T  ((size_t)4740608)   // 2304*2304  (ends 10049024 floats = 40.2 MB)

// ---------------------------------------------------------------- edge grouping
__global__ __launch_bounds__(1024) void k_group(
    const int* __restrict__ esrc, const int* __restrict__ etgt,
    const int* __restrict__ elab, int* __restrict__ cnt,
    int* __restrict__ off, int* __restrict__ edges) {
    __shared__ int lcnt[L];
    __shared__ int loff[L];
    int t = threadIdx.x;  // t == global edge id, blockDim == B*E == 1024
    if (t < L) lcnt[t] = 0;
    __syncthreads();
    int lab = elab[t], src = esrc[t], tgt = etgt[t];
    bool valid = (lab >= 0) && (lab < L) && (src >= 0) && (src < S) && (tgt >= 0) && (tgt < S);
    int mypos = -1;
    if (valid) mypos = atomicAdd(&lcnt[lab], 1);
    __syncthreads();
    if (t == 0) {
        int acc = 0;
        for (int l = 0; l < L; l++) { loff[l] = acc; acc += lcnt[l]; }
    }
    __syncthreads();
    if (valid) edges[loff[lab] + mypos] = t;
    if (t < L) { cnt[t] = lcnt[t]; off[t] = loff[t]; }
}

// ---------------------------------------------------------------- generic 32x32 tiled transpose: out[C][R] = in[R][C]^T
__global__ __launch_bounds__(256) void k_trans(
    const float* __restrict__ in, float* __restrict__ out, int R, int C) {
    __shared__ float T[32][33];
    int c0 = blockIdx.x * 32, r0 = blockIdx.y * 32;
    int tid = threadIdx.x;
    int cc = tid & 31, r8 = tid >> 5;
#pragma unroll
    for (int i = 0; i < 4; i++) {
        int rr = r8 + 8 * i;
        T[rr][cc] = in[(size_t)(r0 + rr) * C + c0 + cc];
    }
    __syncthreads();
    int rr2 = tid & 31, c8 = tid >> 5;
#pragma unroll
    for (int i = 0; i < 4; i++) {
        int cc2 = c8 + 8 * i;
        out[(size_t)(c0 + cc2) * R + r0 + rr2] = T[rr2][cc2];
    }
}

// ---------------------------------------------------------------- GCN as per-label GEMM tiles
#define GK 384
__global__ __launch_bounds__(256) void k_gcn(
    const float* __restrict__ hidden, const float* __restrict__ gcnW,
    const float* __restrict__ gcnb, const int* __restrict__ cnt,
    const int* __restrict__ off, const int* __restrict__ edges,
    const int* __restrict__ esrc, const int* __restrict__ etgt,
    float* __restrict__ gout) {
    int l = blockIdx.y;
    int n = cnt[l];
    if (n == 0) return;
    int row0 = blockIdx.x * 64;
    int kbase = blockIdx.z * GK;
    __shared__ float Ws[32][68];   // [k][row], padded
    __shared__ float Xs[32][34];   // [k][edge]
    __shared__ int srow[32];
    __shared__ int trow[32];
    int tid = threadIdx.x;
    int tx = tid & 15, ty = tid >> 4;
    int o = off[l];
    for (int e0 = 0; e0 < n; e0 += 32) {
        int nv = min(32, n - e0);
        if (tid < 32) {
            int sr = 0, tr = 0;
            if (tid < nv) {
                int g = edges[o + e0 + tid];
                int bb = g / E;
                sr = (bb * S + esrc[g]) * H;
                tr = (bb * S + etgt[g]) * H;
            }
            srow[tid] = sr;
            trow[tid] = tr;
        }
        __syncthreads();
        float acc[4][2];
#pragma unroll
        for (int r = 0; r < 4; r++) { acc[r][0] = 0.f; acc[r][1] = 0.f; }
        for (int kc = 0; kc < GK; kc += 32) {
            int k0 = kbase + kc;
#pragma unroll
            for (int j = 0; j < 2; j++) {
                int f = tid + 256 * j;
                int r = f >> 3, kq = (f & 7) * 4;
                float4 v = *(const float4*)(gcnW + ((size_t)l * H + row0 + r) * H + k0 + kq);
                Ws[kq + 0][r] = v.x; Ws[kq + 1][r] = v.y;
                Ws[kq + 2][r] = v.z; Ws[kq + 3][r] = v.w;
            }
#pragma unroll
            for (int j = 0; j < 4; j++) {
                int f = tid + 256 * j;
                int e = f >> 5, kk = f & 31;
                Xs[kk][e] = hidden[srow[e] + k0 + kk];
            }
            __syncthreads();
#pragma unroll
            for (int k = 0; k < 32; k++) {
                float4 a = *(const float4*)&Ws[k][ty * 4];
                float2 x2 = *(const float2*)&Xs[k][tx * 2];
                acc[0][0] = fmaf(a.x, x2.x, acc[0][0]);
                acc[1][0] = fmaf(a.y, x2.x, acc[1][0]);
                acc[2][0] = fmaf(a.z, x2.x, acc[2][0]);
                acc[3][0] = fmaf(a.w, x2.x, acc[3][0]);
                acc[0][1] = fmaf(a.x, x2.y, acc[0][1]);
                acc[1][1] = fmaf(a.y, x2.y, acc[1][1]);
                acc[2][1] = fmaf(a.z, x2.y, acc[2][1]);
                acc[3][1] = fmaf(a.w, x2.y, acc[3][1]);
            }
            __syncthreads();
        }
        const float* bp = gcnb + l * H + row0 + ty * 4;
        bool addb = (blockIdx.z == 0);
#pragma unroll
        for (int e = 0; e < 2; e++) {
            int ei = tx * 2 + e;
            if (ei < nv) {
                int base = trow[ei] + row0 + ty * 4;
#pragma unroll
                for (int r = 0; r < 4; r++) {
                    float v = acc[r][e];
                    if (addb) v += bp[r];
                    atomicAdd(&gout[base + r], v);
                }
            }
        }
        __syncthreads();
    }
}

// ---------------------------------------------------------------- emb = hidden + relu(gout), plus per-token dots
__global__ __launch_bounds__(256) void k_embdots(
    const float* __restrict__ hidden, const float* __restrict__ gout,
    const float* __restrict__ attnw, const float* __restrict__ antw,
    float* __restrict__ emb, float* __restrict__ tokd) {
    int wave = threadIdx.x >> 6, lane = threadIdx.x & 63;
    int tok = blockIdx.x * 4 + wave;
    const float* hp = hidden + (size_t)tok * H;
    const float* gp = gout + (size_t)tok * H;
    float* ep = emb + (size_t)tok * H;
    float p[7] = {0, 0, 0, 0, 0, 0, 0};
#pragma unroll
    for (int m = 0; m < 12; m++) {
        int k = lane + 64 * m;
        float e = hp[k] + fmaxf(gp[k], 0.f);
        ep[k] = e;
        p[0] = fmaf(attnw[k], e, p[0]);
#pragma unroll
        for (int q = 0; q < 6; q++) p[1 + q] = fmaf(antw[q * H + k], e, p[1 + q]);
    }
#pragma unroll
    for (int q = 0; q < 7; q++) {
        float v = p[q];
#pragma unroll
        for (int d = 32; d; d >>= 1) v += __shfl_down(v, d);
        p[q] = v;
    }
    if (lane == 0) {
        float* o = tokd + (size_t)tok * 8;
#pragma unroll
        for (int q = 0; q < 7; q++) o[q] = p[q];
    }
}

// ---------------------------------------------------------------- G = emb @ W1-blocks^T via pre-transposed inputs
// R5 lesson kept: all accs/prefetch are NAMED scalars (arrays got demoted to
// scratch). R6: 64x64 tile -> 864 blocks (was 432): fixes the 1.7-blocks/CU
// quantization tail + gives 4+ resident blocks/CU for latency hiding.
__global__ __launch_bounds__(256, 4) void k_gemm(
    const float* __restrict__ embT, const float* __restrict__ W1T, float* __restrict__ G) {
    __shared__ float As[32][68];
    __shared__ float Bs[32][68];
    int n0 = blockIdx.x * 64;
    int m0 = blockIdx.y * 64;
    int blk = n0 / D3;          // 2304 % 64 == 0 -> tiles never straddle blocks
    int e0 = n0 - blk * D3;
    int tid = threadIdx.x;
    int tx = tid & 15, ty = tid >> 4;
    const float* Ap = embT + m0;                          // embT[k][m0+..], row stride 512
    const float* Bp = W1T + (size_t)(blk * H) * D3 + e0;  // W1T[blk*768+k][e0+..], row stride D3
    // staging coords: chunk f covers [k = f>>4][col = (f&15)*4]
    int r0 = tid >> 4, q0 = (tid & 15) * 4;
    int r1 = (tid + 256) >> 4, q1 = ((tid + 256) & 15) * 4;
    float4 pa0 = *(const float4*)(Ap + (size_t)r0 * 512 + q0);
    float4 pa1 = *(const float4*)(Ap + (size_t)r1 * 512 + q1);
    float4 pb0 = *(const float4*)(Bp + (size_t)r0 * D3 + q0);
    float4 pb1 = *(const float4*)(Bp + (size_t)r1 * D3 + q1);
    float c00 = 0.f, c01 = 0.f, c02 = 0.f, c03 = 0.f;
    float c10 = 0.f, c11 = 0.f, c12 = 0.f, c13 = 0.f;
    float c20 = 0.f, c21 = 0.f, c22 = 0.f, c23 = 0.f;
    float c30 = 0.f, c31 = 0.f, c32 = 0.f, c33 = 0.f;
    for (int kt = 0; kt < H; kt += 32) {
        *(float4*)&As[r0][q0] = pa0;
        *(float4*)&As[r1][q1] = pa1;
        *(float4*)&Bs[r0][q0] = pb0;
        *(float4*)&Bs[r1][q1] = pb1;
        __syncthreads();
        if (kt + 32 < H) {
            const float* Apn = Ap + (size_t)(kt + 32) * 512;
            const float* Bpn = Bp + (size_t)(kt + 32) * D3;
            pa0 = *(const float4*)(Apn + (size_t)r0 * 512 + q0);
            pa1 = *(const float4*)(Apn + (size_t)r1 * 512 + q1);
            pb0 = *(const float4*)(Bpn + (size_t)r0 * D3 + q0);
            pb1 = *(const float4*)(Bpn + (size_t)r1 * D3 + q1);
        }
#pragma unroll
        for (int k = 0; k < 32; k++) {
            float4 av = *(const float4*)&As[k][ty * 4];
            float4 bv = *(const float4*)&Bs[k][tx * 4];
            c00 = fmaf(av.x, bv.x, c00); c01 = fmaf(av.x, bv.y, c01);
            c02 = fmaf(av.x, bv.z, c02); c03 = fmaf(av.x, bv.w, c03);
            c10 = fmaf(av.y, bv.x, c10); c11 = fmaf(av.y, bv.y, c11);
            c12 = fmaf(av.y, bv.z, c12); c13 = fmaf(av.y, bv.w, c13);
            c20 = fmaf(av.z, bv.x, c20); c21 = fmaf(av.z, bv.y, c21);
            c22 = fmaf(av.z, bv.z, c22); c23 = fmaf(av.z, bv.w, c23);
            c30 = fmaf(av.w, bv.x, c30); c31 = fmaf(av.w, bv.y, c31);
            c32 = fmaf(av.w, bv.z, c32); c33 = fmaf(av.w, bv.w, c33);
        }
        __syncthreads();
    }
    float* g0 = G + (size_t)(m0 + ty * 4 + 0) * N6 + n0 + tx * 4;
    float* g1 = G + (size_t)(m0 + ty * 4 + 1) * N6 + n0 + tx * 4;
    float* g2 = G + (size_t)(m0 + ty * 4 + 2) * N6 + n0 + tx * 4;
    float* g3 = G + (size_t)(m0 + ty * 4 + 3) * N6 + n0 + tx * 4;
    *(float4*)g0 = make_float4(c00, c01, c02, c03);
    *(float4*)g1 = make_float4(c10, c11, c12, c13);
    *(float4*)g2 = make_float4(c20, c21, c22, c23);
    *(float4*)g3 = make_float4(c30, c31, c32, c33);
}

// ---------------------------------------------------------------- span kernel, e-chunked for parallelism
// ms_b2 / attn_b dropped: constant shifts, invariant under top-k / softmax.
__global__ __launch_bounds__(256) void k_span(
    const float* __restrict__ G, const float* __restrict__ tokd,
    const float* __restrict__ b1, const float* __restrict__ w2,
    float* __restrict__ ment, float* __restrict__ sjA, float* __restrict__ siA) {
    int ec = blockIdx.x;
    int start = blockIdx.y;
    int b = blockIdx.z;
    int nw = min(W, S - start);
    int tail = S - start;
    int base = (start <= S - W) ? start * W
             : (S - W + 1) * W + ((W - 1) * W / 2 - tail * (tail + 1) / 2);
    __shared__ float aw[W][W + 1];
    int tid = threadIdx.x;
    const float* td = tokd + (size_t)(b * S) * 8;
    if (tid < nw) {
        int w = tid;  // span of width w+1
        float sc[W];
        float mx = -3.0e38f;
        for (int j = 0; j <= w; j++) { sc[j] = td[(start + j) * 8]; mx = fmaxf(mx, sc[j]); }
        float sum = 0.f;
        for (int j = 0; j <= w; j++) { float e = expf(sc[j] - mx); aw[w][j] = e; sum += e; }
        float inv = 1.f / sum;
        for (int j = 0; j <= w; j++) aw[w][j] *= inv;
        if (ec == 0) {
            float sj = td[start * 8 + 1] + td[(start + w) * 8 + 2];
            float si = td[start * 8 + 4] + td[(start + w) * 8 + 5];
            for (int j = 0; j <= w; j++) {
                sj = fmaf(aw[w][j], td[(start + j) * 8 + 3], sj);
                si = fmaf(aw[w][j], td[(start + j) * 8 + 6], si);
            }
            sjA[b * NSPAN + base + w] = sj;
            siA[b * NSPAN + base + w] = si;
        }
    }
    __syncthreads();
    int e = ec * 256 + tid;
    const float* Gb = G + (size_t)(b * S) * N6;
    float a = Gb[(size_t)start * N6 + e] + b1[e];
    float w2e = w2[e];
    float cj[W], bm[W];
#pragma unroll
    for (int j = 0; j < W; j++) {
        if (j < nw) {
            cj[j] = Gb[(size_t)(start + j) * N6 + 2 * D3 + e];
            bm[j] = Gb[(size_t)(start + j) * N6 + D3 + e];
        } else { cj[j] = 0.f; bm[j] = 0.f; }
    }
    int lane = tid & 63;
#pragma unroll
    for (int w = 0; w < W; w++) {
        float v = 0.f;
        if (w < nw) {
            float pre = a + bm[w];
#pragma unroll
            for (int j = 0; j <= w; j++) pre = fmaf(aw[w][j], cj[j], pre);
            v = fmaxf(pre, 0.f) * w2e;
        }
#pragma unroll
        for (int d = 32; d; d >>= 1) v += __shfl_down(v, d);
        if (lane == 0 && w < nw) atomicAdd(&ment[b * NSPAN + base + w], v);
    }
}

// ---------------------------------------------------------------- fused top-k (radix select) + antecedent log-softmax
__global__ __launch_bounds__(256) void k_topkant(
    const float* __restrict__ ment, const float* __restrict__ sjA,
    const float* __restrict__ siA, const float* __restrict__ antb,
    float* __restrict__ out) {
    __shared__ unsigned int uv[NSPAN];
    __shared__ int hist[4][256];
    __shared__ int suf[256];
    __shared__ int cand_i[160];
    __shared__ unsigned int cand_u[160];
    __shared__ int ncand;
    __shared__ unsigned int s_prefix;
    __shared__ int s_kk;
    __shared__ float selj[KTOP];
    __shared__ float seli[KTOP];
    int b = blockIdx.x, tid = threadIdx.x;
    int wave = tid >> 6, lane = tid & 63;
    for (int n = tid; n < NSPAN; n += 256) {
        unsigned int u = __float_as_uint(ment[b * NSPAN + n]);
        uv[n] = (u & 0x80000000u) ? ~u : (u | 0x80000000u);
    }
    if (tid == 0) { s_prefix = 0u; s_kk = KTOP; ncand = 0; }
    __syncthreads();
    for (int pass = 3; pass >= 0; pass--) {
        int shift = pass * 8;
#pragma unroll
        for (int q = 0; q < 4; q++) hist[q][tid] = 0;
        __syncthreads();
        unsigned int pref = s_prefix;
        unsigned int pmask = (pass == 3) ? 0u : (0xFFFFFFFFu << (shift + 8));
        for (int n = tid; n < NSPAN; n += 256) {
            unsigned int u = uv[n];
            if ((u & pmask) == pref) atomicAdd(&hist[wave][(u >> shift) & 255], 1);
        }
        __syncthreads();
        suf[tid] = hist[0][tid] + hist[1][tid] + hist[2][tid] + hist[3][tid];
        __syncthreads();
        for (int d2 = 1; d2 < 256; d2 <<= 1) {
            int y = suf[tid] + ((tid + d2 < 256) ? suf[tid + d2] : 0);
            __syncthreads();
            suf[tid] = y;
            __syncthreads();
        }
        int kk = s_kk;
        __syncthreads();
        if (suf[tid] >= kk && (tid == 255 || suf[tid + 1] < kk)) {
            s_prefix = pref | ((unsigned int)tid << shift);
            s_kk = kk - ((tid == 255) ? 0 : suf[tid + 1]);
        }
        __syncthreads();
    }
    unsigned int uk = s_prefix;   // exact k-th largest key
    for (int n = tid; n < NSPAN; n += 256) {
        if (uv[n] >= uk) {
            int p = atomicAdd(&ncand, 1);
            if (p < 160) { cand_i[p] = n; cand_u[p] = uv[n]; }
        }
    }
    __syncthreads();
    int nc = min(ncand, 160);
    for (int c = tid; c < nc; c += 256) {
        unsigned int u = cand_u[c];
        int idx = cand_i[c];
        int rank = 0;
        for (int d = 0; d < nc; d++) {
            unsigned int ud = cand_u[d];
            if (ud > u || (ud == u && cand_i[d] < idx)) rank++;
        }
        if (rank < KTOP) {
            selj[rank] = sjA[b * NSPAN + idx];
            seli[rank] = siA[b * NSPAN + idx];
        }
    }
    __syncthreads();
    // antecedent rows: wave per row, lanes cover cols {lane, lane+64} of 103
    float ab = antb[0];
    for (int i = wave; i < KTOP; i += 4) {
        float si = seli[i];
        float v0, v1;
        if (lane == 0) v0 = 0.f;
        else {
            int j = lane - 1;
            v0 = (j >= i) ? -1e10f : (selj[j] + si + ab);
        }
        int c1 = lane + 64;
        bool v1ok = (c1 <= KTOP);
        if (v1ok) {
            int j = c1 - 1;
            v1 = (j >= i) ? -1e10f : (selj[j] + si + ab);
        } else v1 = -3.0e38f;
        float mx = fmaxf(v0, v1);
#pragma unroll
        for (int d = 32; d; d >>= 1) mx = fmaxf(mx, __shfl_down(mx, d));
        mx = __shfl(mx, 0);
        float e0 = expf(v0 - mx);
        float e1 = v1ok ? expf(v1 - mx) : 0.f;
        float sm = e0 + e1;
#pragma unroll
        for (int d = 32; d; d >>= 1) sm += __shfl_down(sm, d);
        sm = __shfl(sm, 0);
        float* op = out + (size_t)(b * KTOP + i) * (KTOP + 1);
        op[lane] = logf(e0 / sm + 1e-10f);
        if (v1ok) op[c1] = logf(e1 / sm + 1e-10f);
    }
}

extern "C" void kernel_launch(void* const* d_in, const int* in_sizes, int n_in,
                              void* d_out, int out_size, void* d_ws, size_t ws_size,
                              hipStream_t stream) {
    (void)in_sizes; (void)n_in; (void)out_size; (void)ws_size;
    const float* hidden = (const float*)d_in[0];
    const int*   esrc   = (const int*)d_in[2];
    const int*   etgt   = (const int*)d_in[3];
    const int*   elab   = (const int*)d_in[4];
    const float* gcnW   = (const float*)d_in[5];
    const float* gcnb   = (const float*)d_in[6];
    const float* attnw  = (const float*)d_in[7];
    const float* msW1   = (const float*)d_in[9];
    const float* msb1   = (const float*)d_in[10];
    const float* msw2   = (const float*)d_in[11];
    const float* antw   = (const float*)d_in[13];
    const float* antb   = (const float*)d_in[14];
    float* out = (float*)d_out;

    float* wsf  = (float*)d_ws;
    float* gout = wsf + OFF_GOUT;
    float* emb  = wsf + OFF_EMB;
    float* G    = wsf + OFF_G;
    float* tokd = wsf + OFF_TOKD;
    float* ment = wsf + OFF_MENT;
    float* sjA  = wsf + OFF_SJ;
    float* siA  = wsf + OFF_SI;
    float* embT = wsf + OFF_EMBT;
    float* W1T  = wsf + OFF_W1T;
    int* wsi   = (int*)(wsf + OFF_INT);
    int* cnt   = wsi;
    int* off   = wsi + 64;
    int* edges = wsi + 128;

    hipMemsetAsync(gout, 0, (size_t)B * S * H * sizeof(float), stream);
    hipMemsetAsync(ment, 0, (size_t)B * NSPAN * sizeof(float), stream);
    k_group<<<1, B * E, 0, stream>>>(esrc, etgt, elab, cnt, off, edges);
    k_trans<<<dim3(D3 / 32, D3 / 32), 256, 0, stream>>>(msW1, W1T, D3, D3);
    k_gcn<<<dim3(12, L, 2), 256, 0, stream>>>(hidden, gcnW, gcnb, cnt, off, edges, esrc, etgt, gout);
    k_embdots<<<B * S / 4, 256, 0, stream>>>(hidden, gout, attnw, antw, emb, tokd);
    k_trans<<<dim3(H / 32, (B * S) / 32), 256, 0, stream>>>(emb, embT, B * S, H);
    k_gemm<<<dim3(N6 / 64, (B * S) / 64), 256, 0, stream>>>(embT, W1T, G);
    k_span<<<dim3(D3 / 256, S, B), 256, 0, stream>>>(G, tokd, msb1, msw2, ment, sjA, siA);
    k_topkant<<<B, 256, 0, stream>>>(ment, sjA, siA, antb, out);
}